// Round 1
// baseline (122.056 us; speedup 1.0000x reference)
//
#include <hip/hip_runtime.h>
#include <hip/hip_bf16.h>

#define B_  32
#define T_  768
#define C_  256
#define H_  64
#define BT_ (B_*T_)

using short8 = __attribute__((ext_vector_type(8))) short;
using f32x4  = __attribute__((ext_vector_type(4))) float;

__device__ __forceinline__ ushort f2bf(float f) {
    union { float f; unsigned u; } v; v.f = f;
    unsigned u = v.u;
    return (ushort)((u + 0x7FFFu + ((u >> 16) & 1u)) >> 16);
}

// ---------------- QKV projection ----------------
// grid 384 blocks x 256 threads; each block computes 64 rows x (3x64) outputs.
// A-fragments (x rows) held in regs as bf16; W^T staged per-matrix in LDS.
__global__ __launch_bounds__(256) void qkv_proj_kernel(
    const float* __restrict__ x, const float* __restrict__ wq,
    const float* __restrict__ wk, const float* __restrict__ wv,
    ushort* __restrict__ qkv)
{
    __shared__ ushort wT[64][264];   // W^T bf16, padded stride (264u = 528B, 16B-aligned)
    const int tid   = threadIdx.x;
    const int wv_id = tid >> 6;      // wave 0..3
    const int lane  = tid & 63;
    const int g     = lane >> 4;     // k-group 0..3
    const int c     = lane & 15;     // row (A) / col (B)
    const int row   = blockIdx.x*64 + wv_id*16 + c;

    // load x row fragments fp32 -> bf16, 8 chunks of K=32
    short8 a[8];
    const float* xr = x + row*C_;
    #pragma unroll
    for (int ch = 0; ch < 8; ++ch) {
        const float4 f0 = *(const float4*)(xr + ch*32 + g*8);
        const float4 f1 = *(const float4*)(xr + ch*32 + g*8 + 4);
        short8 t;
        t[0]=(short)f2bf(f0.x); t[1]=(short)f2bf(f0.y); t[2]=(short)f2bf(f0.z); t[3]=(short)f2bf(f0.w);
        t[4]=(short)f2bf(f1.x); t[5]=(short)f2bf(f1.y); t[6]=(short)f2bf(f1.z); t[7]=(short)f2bf(f1.w);
        a[ch] = t;
    }

    for (int m = 0; m < 3; ++m) {
        const float* wsrc = (m == 0) ? wq : ((m == 1) ? wk : wv);
        // stage W^T (bf16): wT[h][k] = W[k][h]
        for (int i = tid; i < C_*H_; i += 256)
            wT[i & 63][i >> 6] = f2bf(wsrc[i]);
        __syncthreads();

        ushort* dst = qkv + m*BT_*H_ + (blockIdx.x*64 + wv_id*16)*H_;
        #pragma unroll
        for (int jn = 0; jn < 4; ++jn) {
            f32x4 acc = {0.f, 0.f, 0.f, 0.f};
            #pragma unroll
            for (int ch = 0; ch < 8; ++ch) {
                const short8 bw = *(const short8*)(&wT[jn*16 + c][ch*32 + g*8]);
                acc = __builtin_amdgcn_mfma_f32_16x16x32_bf16(a[ch], bw, acc, 0, 0, 0);
            }
            // C/D: col = lane&15, row = (lane>>4)*4 + r   [measured m89/m91]
            #pragma unroll
            for (int r = 0; r < 4; ++r)
                dst[(g*4 + r)*H_ + jn*16 + c] = f2bf(acc[r]);
        }
        __syncthreads();
    }
}

// ---------------- causal flash attention ----------------
// grid 384 = (B x 12 q-tiles), 256 threads = 4 waves x 16 q-rows.
__global__ __launch_bounds__(256) void attn_kernel(
    const ushort* __restrict__ qkv, float* __restrict__ out)
{
    __shared__ ushort vT [64][72];      // V^T, padded stride 72u = 144B (16B-aligned)
    __shared__ ushort pls[4][16][72];   // per-wave P tile

    const int tid   = threadIdx.x;
    const int wv_id = tid >> 6;
    const int lane  = tid & 63;
    const int g     = lane >> 4;
    const int c     = lane & 15;
    const int qt    = 11 - (blockIdx.x >> 5);   // big tiles dispatched first
    const int b     = blockIdx.x & 31;

    const ushort* kbase = qkv + BT_*H_;
    const ushort* vbase = qkv + 2*BT_*H_;

    // Q fragments (row = lane&15, k-chunks of 32 over H)
    short8 aq[2];
    const ushort* qp = qkv + (b*T_ + qt*64 + wv_id*16 + c)*H_;
    #pragma unroll
    for (int ch = 0; ch < 2; ++ch)
        aq[ch] = *(const short8*)(qp + ch*32 + g*8);

    float m_[4], l_[4];
    f32x4 o[4];
    #pragma unroll
    for (int r = 0; r < 4; ++r) { m_[r] = -INFINITY; l_[r] = 0.f; }
    #pragma unroll
    for (int jh = 0; jh < 4; ++jh) o[jh] = (f32x4){0.f, 0.f, 0.f, 0.f};

    for (int kt = 0; kt <= qt; ++kt) {
        __syncthreads();                 // protect vT reads of previous iter
        // stage V^T: coalesced 16B global reads, scattered LDS writes
        const ushort* vsrc = vbase + (b*T_ + kt*64)*H_;
        #pragma unroll
        for (int it = 0; it < 2; ++it) {
            const int i   = tid + it*256;     // 0..511
            const int r   = i >> 3;           // kv row 0..63
            const int seg = (i & 7) * 8;      // h segment
            const short8 u = *(const short8*)(vsrc + r*H_ + seg);
            #pragma unroll
            for (int e = 0; e < 8; ++e) vT[seg + e][r] = (ushort)u[e];
        }
        __syncthreads();

        // S = Q K^T  (B operand loaded directly from global K rows)
        f32x4 s[4];
        #pragma unroll
        for (int j = 0; j < 4; ++j) {
            f32x4 acc = {0.f, 0.f, 0.f, 0.f};
            #pragma unroll
            for (int ch = 0; ch < 2; ++ch) {
                const short8 bk = *(const short8*)(kbase + (b*T_ + kt*64 + j*16 + c)*H_ + ch*32 + g*8);
                acc = __builtin_amdgcn_mfma_f32_16x16x32_bf16(aq[ch], bk, acc, 0, 0, 0);
            }
            s[j] = acc;
        }

        // scale + causal mask (diagonal tile only)
        const bool diag = (kt == qt);
        #pragma unroll
        for (int j = 0; j < 4; ++j) {
            #pragma unroll
            for (int r = 0; r < 4; ++r) {
                float v = s[j][r] * 0.125f;
                if (diag && (j*16 + c > wv_id*16 + g*4 + r)) v = -1e30f;
                s[j][r] = v;
            }
        }

        // online softmax per q-row (row lives across the 16 lanes sharing g)
        #pragma unroll
        for (int r = 0; r < 4; ++r) {
            float tm = fmaxf(fmaxf(s[0][r], s[1][r]), fmaxf(s[2][r], s[3][r]));
            tm = fmaxf(tm, __shfl_xor(tm, 1));
            tm = fmaxf(tm, __shfl_xor(tm, 2));
            tm = fmaxf(tm, __shfl_xor(tm, 4));
            tm = fmaxf(tm, __shfl_xor(tm, 8));
            const float mn = fmaxf(m_[r], tm);
            const float al = __expf(m_[r] - mn);
            m_[r] = mn;
            float ps = 0.f;
            #pragma unroll
            for (int j = 0; j < 4; ++j) {
                const float p = __expf(s[j][r] - mn);
                s[j][r] = p;
                ps += p;
            }
            ps += __shfl_xor(ps, 1);
            ps += __shfl_xor(ps, 2);
            ps += __shfl_xor(ps, 4);
            ps += __shfl_xor(ps, 8);
            l_[r] = l_[r]*al + ps;
            #pragma unroll
            for (int jh = 0; jh < 4; ++jh) o[jh][r] *= al;
        }

        // P -> LDS (bf16), wave-private region: no block sync needed
        #pragma unroll
        for (int j = 0; j < 4; ++j) {
            #pragma unroll
            for (int r = 0; r < 4; ++r)
                pls[wv_id][g*4 + r][j*16 + c] = f2bf(s[j][r]);
        }

        // O += P V   (A = P from LDS, B = V via vT; same k-map both sides)
        #pragma unroll
        for (int c2 = 0; c2 < 2; ++c2) {
            const short8 ap = *(const short8*)(&pls[wv_id][c][c2*32 + g*8]);
            #pragma unroll
            for (int jh = 0; jh < 4; ++jh) {
                const short8 bv = *(const short8*)(&vT[jh*16 + c][c2*32 + g*8]);
                o[jh] = __builtin_amdgcn_mfma_f32_16x16x32_bf16(ap, bv, o[jh], 0, 0, 0);
            }
        }
    }

    // epilogue: divide by softmax denom, write fp32
    float* op = out + (b*T_ + qt*64 + wv_id*16)*H_;
    #pragma unroll
    for (int jh = 0; jh < 4; ++jh) {
        #pragma unroll
        for (int r = 0; r < 4; ++r)
            op[(g*4 + r)*H_ + jh*16 + c] = o[jh][r] / l_[r];
    }
}

extern "C" void kernel_launch(void* const* d_in, const int* in_sizes, int n_in,
                              void* d_out, int out_size, void* d_ws, size_t ws_size,
                              hipStream_t stream) {
    const float* x  = (const float*)d_in[0];
    const float* wq = (const float*)d_in[1];
    const float* wk = (const float*)d_in[2];
    const float* wv = (const float*)d_in[3];
    ushort* qkv = (ushort*)d_ws;   // 3 * 24576 * 64 * 2 B = 9.44 MB scratch (bf16 q,k,v)

    qkv_proj_kernel<<<dim3(BT_/64), dim3(256), 0, stream>>>(x, wq, wk, wv, qkv);
    attn_kernel<<<dim3(B_*12), dim3(256), 0, stream>>>(qkv, (float*)d_out);
}

// Round 3
// 108.931 us; speedup vs baseline: 1.1205x; 1.1205x over previous
//
#include <hip/hip_runtime.h>
#include <hip/hip_bf16.h>

#define B_  32
#define T_  768
#define C_  256
#define H_  64
#define BT_ (B_*T_)
#define WT_OFF (3*BT_*H_)   // ushort offset of wT[3][64][256] in ws

using short8 = __attribute__((ext_vector_type(8))) short;
using f32x4  = __attribute__((ext_vector_type(4))) float;

__device__ __forceinline__ ushort f2bf(float f) {
    union { float f; unsigned u; } v; v.f = f;
    unsigned u = v.u;
    return (ushort)((u + 0x7FFFu + ((u >> 16) & 1u)) >> 16);
}

// ---------------- W prep: wT[m][h][k] = bf16(W_m[k][h]) ----------------
// 192 blocks x 256 threads, coalesced writes, strided (L2-cached) reads.
__global__ __launch_bounds__(256) void prep_w_kernel(
    const float* __restrict__ wq, const float* __restrict__ wk,
    const float* __restrict__ wv, ushort* __restrict__ ws)
{
    const int idx = blockIdx.x*256 + threadIdx.x;   // 0..49151
    const int m = idx >> 14, r = idx & 16383;
    const int h = r >> 8, k = r & 255;
    const float* w = (m == 0) ? wq : (m == 1) ? wk : wv;
    ws[WT_OFF + idx] = f2bf(w[k*H_ + h]);
}

// ---------------- QKV projection ----------------
// 384 blocks x 256 threads; block computes 64 rows x (3x64).
// q,k written natural [BT][H]; v written transposed vT[H][BT].
__global__ __launch_bounds__(256) void qkv_proj_kernel(
    const float* __restrict__ x, ushort* __restrict__ ws)
{
    __shared__ ushort wT[64][264];   // stride 528B: fragment reads uniform across banks
    __shared__ ushort vls[64][72];   // output staging tile, stride 144B
    const int tid   = threadIdx.x;
    const int wv_id = tid >> 6;
    const int lane  = tid & 63;
    const int g     = lane >> 4;
    const int c     = lane & 15;
    const int rowbase = blockIdx.x*64;
    const int row     = rowbase + wv_id*16 + c;
    const int sh = tid >> 2, ss = tid & 3;          // coop-copy coords

    // x row fragments fp32 -> bf16 (16 x float4 loads)
    short8 a[8];
    const float* xr = x + row*C_;
    #pragma unroll
    for (int ch = 0; ch < 8; ++ch) {
        const float4 f0 = *(const float4*)(xr + ch*32 + g*8);
        const float4 f1 = *(const float4*)(xr + ch*32 + g*8 + 4);
        short8 t;
        t[0]=(short)f2bf(f0.x); t[1]=(short)f2bf(f0.y); t[2]=(short)f2bf(f0.z); t[3]=(short)f2bf(f0.w);
        t[4]=(short)f2bf(f1.x); t[5]=(short)f2bf(f1.y); t[6]=(short)f2bf(f1.z); t[7]=(short)f2bf(f1.w);
        a[ch] = t;
    }

    const ushort* wtg = ws + WT_OFF;
    // stage W^T(m=0): 16 x b128 copies per thread-row segment
    #pragma unroll
    for (int i = 0; i < 8; ++i)
        *(short8*)&wT[sh][ss*64 + i*8] = *(const short8*)(wtg + sh*256 + ss*64 + i*8);
    __syncthreads();

    for (int m = 0; m < 3; ++m) {
        // MFMA + stage output tile into vls
        #pragma unroll
        for (int jn = 0; jn < 4; ++jn) {
            f32x4 acc = {0.f, 0.f, 0.f, 0.f};
            #pragma unroll
            for (int ch = 0; ch < 8; ++ch) {
                const short8 bw = *(const short8*)(&wT[jn*16 + c][ch*32 + g*8]);
                acc = __builtin_amdgcn_mfma_f32_16x16x32_bf16(a[ch], bw, acc, 0, 0, 0);
            }
            // C/D: col = lane&15, row = (lane>>4)*4 + r
            if (m < 2) {
                #pragma unroll
                for (int r = 0; r < 4; ++r)
                    vls[wv_id*16 + g*4 + r][jn*16 + c] = f2bf(acc[r]);   // [row][h]
            } else {
                #pragma unroll
                for (int r = 0; r < 4; ++r)
                    vls[jn*16 + c][wv_id*16 + g*4 + r] = f2bf(acc[r]);   // [h][row]
            }
        }
        __syncthreads();
        // coop store of vls (coalesced b128) + stage next W
        {
            ushort* dst = (m < 2)
                ? (ws + m*BT_*H_ + (rowbase + sh)*H_ + ss*16)            // q/k natural
                : (ws + 2*BT_*H_ + sh*BT_ + rowbase + ss*16);            // vT[h][bt]
            *(short8*)(dst)     = *(const short8*)&vls[sh][ss*16];
            *(short8*)(dst + 8) = *(const short8*)&vls[sh][ss*16 + 8];
            if (m < 2) {
                const ushort* src = wtg + (m+1)*16384 + sh*256 + ss*64;
                #pragma unroll
                for (int i = 0; i < 8; ++i)
                    *(short8*)&wT[sh][ss*64 + i*8] = *(const short8*)(src + i*8);
            }
        }
        __syncthreads();
    }
}

// ---------------- causal flash attention ----------------
// 384 blocks (B x 12 q-tiles, heavy first) x 256 threads = 4 waves x 16 q-rows.
// K/V tiles double-buffered in LDS; loads issued early (reg-staged), 1 barrier/iter.
__global__ __launch_bounds__(256) void attn_kernel(
    const ushort* __restrict__ ws, float* __restrict__ out)
{
    __shared__ ushort kls[2][64][72];
    __shared__ ushort vls[2][64][72];
    __shared__ ushort pls[4][16][72];

    const int tid   = threadIdx.x;
    const int wv_id = tid >> 6;
    const int lane  = tid & 63;
    const int g     = lane >> 4;
    const int c     = lane & 15;
    const int qt    = 11 - (blockIdx.x >> 5);   // heavy tiles first
    const int b     = blockIdx.x & 31;
    const int nkt   = qt + 1;
    const int sh = tid >> 2, ss = tid & 3;

    const ushort* kg  = ws + BT_*H_ + b*T_*H_;     // K natural rows
    const ushort* vtg = ws + 2*BT_*H_ + b*T_;      // vT rows: +h*BT_

    // Q fragments
    short8 aq[2];
    const ushort* qp = ws + (b*T_ + qt*64 + wv_id*16 + c)*H_;
    aq[0] = *(const short8*)(qp + g*8);
    aq[1] = *(const short8*)(qp + 32 + g*8);

    float m_[4], l_[4];
    f32x4 o[4];
    #pragma unroll
    for (int r = 0; r < 4; ++r) { m_[r] = -INFINITY; l_[r] = 0.f; }
    #pragma unroll
    for (int jh = 0; jh < 4; ++jh) o[jh] = (f32x4){0.f, 0.f, 0.f, 0.f};

    short8 kreg0, kreg1, vreg0, vreg1;
    #define LOAD_TILES(kt_) do { \
        const ushort* ksrc = kg + ((kt_)*64 + sh)*H_ + ss*16;       \
        kreg0 = *(const short8*)ksrc; kreg1 = *(const short8*)(ksrc + 8); \
        const ushort* vsrc = vtg + sh*BT_ + (kt_)*64 + ss*16;       \
        vreg0 = *(const short8*)vsrc; vreg1 = *(const short8*)(vsrc + 8); \
    } while (0)
    #define WRITE_TILES(bi_) do { \
        *(short8*)&kls[bi_][sh][ss*16]     = kreg0; \
        *(short8*)&kls[bi_][sh][ss*16 + 8] = kreg1; \
        *(short8*)&vls[bi_][sh][ss*16]     = vreg0; \
        *(short8*)&vls[bi_][sh][ss*16 + 8] = vreg1; \
    } while (0)

    LOAD_TILES(0);
    WRITE_TILES(0);
    __syncthreads();

    int cur = 0;
    for (int kt = 0; kt < nkt; ++kt) {
        const bool more = (kt + 1 < nkt);
        if (more) LOAD_TILES(kt + 1);     // issue early: HBM/L2 latency hides under compute

        // S = Q K^T
        f32x4 s[4];
        #pragma unroll
        for (int j = 0; j < 4; ++j) {
            f32x4 acc = {0.f, 0.f, 0.f, 0.f};
            #pragma unroll
            for (int ch = 0; ch < 2; ++ch) {
                const short8 bk = *(const short8*)(&kls[cur][j*16 + c][ch*32 + g*8]);
                acc = __builtin_amdgcn_mfma_f32_16x16x32_bf16(aq[ch], bk, acc, 0, 0, 0);
            }
            s[j] = acc;
        }

        // scale + causal mask (diagonal tile only)
        const bool diag = (kt == qt);
        #pragma unroll
        for (int j = 0; j < 4; ++j) {
            #pragma unroll
            for (int r = 0; r < 4; ++r) {
                float v = s[j][r] * 0.125f;
                if (diag && (j*16 + c > wv_id*16 + g*4 + r)) v = -1e30f;
                s[j][r] = v;
            }
        }

        // online softmax per q-row (row spans the 16 lanes sharing g)
        #pragma unroll
        for (int r = 0; r < 4; ++r) {
            float tm = fmaxf(fmaxf(s[0][r], s[1][r]), fmaxf(s[2][r], s[3][r]));
            tm = fmaxf(tm, __shfl_xor(tm, 1));
            tm = fmaxf(tm, __shfl_xor(tm, 2));
            tm = fmaxf(tm, __shfl_xor(tm, 4));
            tm = fmaxf(tm, __shfl_xor(tm, 8));
            const float mn = fmaxf(m_[r], tm);
            const float al = __expf(m_[r] - mn);
            m_[r] = mn;
            float ps = 0.f;
            #pragma unroll
            for (int j = 0; j < 4; ++j) {
                const float p = __expf(s[j][r] - mn);
                s[j][r] = p;
                ps += p;
            }
            ps += __shfl_xor(ps, 1);
            ps += __shfl_xor(ps, 2);
            ps += __shfl_xor(ps, 4);
            ps += __shfl_xor(ps, 8);
            l_[r] = l_[r]*al + ps;
            #pragma unroll
            for (int jh = 0; jh < 4; ++jh) o[jh][r] *= al;
        }

        // P -> LDS (wave-private, no barrier needed)
        #pragma unroll
        for (int j = 0; j < 4; ++j) {
            #pragma unroll
            for (int r = 0; r < 4; ++r)
                pls[wv_id][g*4 + r][j*16 + c] = f2bf(s[j][r]);
        }

        // O += P V
        #pragma unroll
        for (int c2 = 0; c2 < 2; ++c2) {
            const short8 ap = *(const short8*)(&pls[wv_id][c][c2*32 + g*8]);
            #pragma unroll
            for (int jh = 0; jh < 4; ++jh) {
                const short8 bv = *(const short8*)(&vls[cur][jh*16 + c][c2*32 + g*8]);
                o[jh] = __builtin_amdgcn_mfma_f32_16x16x32_bf16(ap, bv, o[jh], 0, 0, 0);
            }
        }

        if (more) WRITE_TILES(cur ^ 1);
        __syncthreads();
        cur ^= 1;
    }

    // epilogue
    float* op = out + (b*T_ + qt*64 + wv_id*16)*H_;
    #pragma unroll
    for (int r = 0; r < 4; ++r) {
        const float inv = 1.0f / l_[r];
        #pragma unroll
        for (int jh = 0; jh < 4; ++jh)
            op[(g*4 + r)*H_ + jh*16 + c] = o[jh][r] * inv;
    }
    #undef LOAD_TILES
    #undef WRITE_TILES
}

extern "C" void kernel_launch(void* const* d_in, const int* in_sizes, int n_in,
                              void* d_out, int out_size, void* d_ws, size_t ws_size,
                              hipStream_t stream) {
    const float* x  = (const float*)d_in[0];
    const float* wq = (const float*)d_in[1];
    const float* wk = (const float*)d_in[2];
    const float* wv = (const float*)d_in[3];
    ushort* ws = (ushort*)d_ws;   // q,k [BT][H]; vT [H][BT]; wT[3][64][256] : ~9.5 MB

    prep_w_kernel<<<dim3(192), dim3(256), 0, stream>>>(wq, wk, wv, ws);
    qkv_proj_kernel<<<dim3(BT_/64), dim3(256), 0, stream>>>(x, ws);
    attn_kernel<<<dim3(B_*12), dim3(256), 0, stream>>>(ws, (float*)d_out);
}

// Round 4
// 103.776 us; speedup vs baseline: 1.1762x; 1.0497x over previous
//
#include <hip/hip_runtime.h>
#include <hip/hip_bf16.h>

#define B_  32
#define T_  768
#define C_  256
#define H_  64
#define BT_ (B_*T_)
#define WT_OFF (3*BT_*H_)   // ushort offset of wT[3][64][256] in ws

using short8 = __attribute__((ext_vector_type(8))) short;
using f32x4  = __attribute__((ext_vector_type(4))) float;

__device__ __forceinline__ ushort f2bf(float f) {
    union { float f; unsigned u; } v; v.f = f;
    unsigned u = v.u;
    return (ushort)((u + 0x7FFFu + ((u >> 16) & 1u)) >> 16);
}

// ---------------- W prep: wT[m][h][k] = bf16(W_m[k][h]) ----------------
__global__ __launch_bounds__(256) void prep_w_kernel(
    const float* __restrict__ wq, const float* __restrict__ wk,
    const float* __restrict__ wv, ushort* __restrict__ ws)
{
    const int idx = blockIdx.x*256 + threadIdx.x;   // 0..49151
    const int m = idx >> 14, r = idx & 16383;
    const int h = r >> 8, k = r & 255;
    const float* w = (m == 0) ? wq : (m == 1) ? wk : wv;
    ws[WT_OFF + idx] = f2bf(w[k*H_ + h]);
}

// ---------------- QKV projection ----------------
// 384 blocks x 256 threads; block computes 64 rows x (3x64).
// q (pre-scaled by 1/8), k natural [BT][H]; v transposed vT[H][BT].
__global__ __launch_bounds__(256) void qkv_proj_kernel(
    const float* __restrict__ x, ushort* __restrict__ ws)
{
    __shared__ ushort wT[64][264];
    __shared__ ushort vls[64][72];
    const int tid   = threadIdx.x;
    const int wv_id = tid >> 6;
    const int lane  = tid & 63;
    const int g     = lane >> 4;
    const int c     = lane & 15;
    const int rowbase = blockIdx.x*64;
    const int row     = rowbase + wv_id*16 + c;
    const int sh = tid >> 2, ss = tid & 3;

    short8 a[8];
    const float* xr = x + row*C_;
    #pragma unroll
    for (int ch = 0; ch < 8; ++ch) {
        const float4 f0 = *(const float4*)(xr + ch*32 + g*8);
        const float4 f1 = *(const float4*)(xr + ch*32 + g*8 + 4);
        short8 t;
        t[0]=(short)f2bf(f0.x); t[1]=(short)f2bf(f0.y); t[2]=(short)f2bf(f0.z); t[3]=(short)f2bf(f0.w);
        t[4]=(short)f2bf(f1.x); t[5]=(short)f2bf(f1.y); t[6]=(short)f2bf(f1.z); t[7]=(short)f2bf(f1.w);
        a[ch] = t;
    }

    const ushort* wtg = ws + WT_OFF;
    #pragma unroll
    for (int i = 0; i < 8; ++i)
        *(short8*)&wT[sh][ss*64 + i*8] = *(const short8*)(wtg + sh*256 + ss*64 + i*8);
    __syncthreads();

    for (int m = 0; m < 3; ++m) {
        #pragma unroll
        for (int jn = 0; jn < 4; ++jn) {
            f32x4 acc = {0.f, 0.f, 0.f, 0.f};
            #pragma unroll
            for (int ch = 0; ch < 8; ++ch) {
                const short8 bw = *(const short8*)(&wT[jn*16 + c][ch*32 + g*8]);
                acc = __builtin_amdgcn_mfma_f32_16x16x32_bf16(a[ch], bw, acc, 0, 0, 0);
            }
            // C/D: col = lane&15, row = (lane>>4)*4 + r
            if (m == 0) {
                #pragma unroll
                for (int r = 0; r < 4; ++r)
                    vls[wv_id*16 + g*4 + r][jn*16 + c] = f2bf(acc[r] * 0.125f); // q pre-scaled
            } else if (m == 1) {
                #pragma unroll
                for (int r = 0; r < 4; ++r)
                    vls[wv_id*16 + g*4 + r][jn*16 + c] = f2bf(acc[r]);
            } else {
                #pragma unroll
                for (int r = 0; r < 4; ++r)
                    vls[jn*16 + c][wv_id*16 + g*4 + r] = f2bf(acc[r]);   // [h][row]
            }
        }
        __syncthreads();
        {
            ushort* dst = (m < 2)
                ? (ws + m*BT_*H_ + (rowbase + sh)*H_ + ss*16)
                : (ws + 2*BT_*H_ + sh*BT_ + rowbase + ss*16);
            *(short8*)(dst)     = *(const short8*)&vls[sh][ss*16];
            *(short8*)(dst + 8) = *(const short8*)&vls[sh][ss*16 + 8];
            if (m < 2) {
                const ushort* src = wtg + (m+1)*16384 + sh*256 + ss*64;
                #pragma unroll
                for (int i = 0; i < 8; ++i)
                    *(short8*)&wT[sh][ss*64 + i*8] = *(const short8*)(src + i*8);
            }
        }
        __syncthreads();
    }
}

// ---------------- causal flash attention ----------------
// 384 blocks (B x 12 q-tiles, heavy first) x 256 threads = 4 waves x 16 q-rows.
// Swapped QK^T (D = S^T tile): each lane owns q-row (lane&15) -> lane-local softmax.
__global__ __launch_bounds__(256) void attn_kernel(
    const ushort* __restrict__ ws, float* __restrict__ out)
{
    __shared__ ushort kls[2][64][72];
    __shared__ ushort vls[2][64][72];
    __shared__ ushort pls[4][16][72];

    const int tid   = threadIdx.x;
    const int wv_id = tid >> 6;
    const int lane  = tid & 63;
    const int g     = lane >> 4;
    const int c     = lane & 15;
    const int qt    = 11 - (blockIdx.x >> 5);   // heavy tiles first
    const int b     = blockIdx.x & 31;
    const int nkt   = qt + 1;
    const int sh = tid >> 2, ss = tid & 3;

    const ushort* kg  = ws + BT_*H_ + b*T_*H_;     // K natural rows
    const ushort* vtg = ws + 2*BT_*H_ + b*T_;      // vT rows: +h*BT_

    // Q fragments (q pre-scaled by 1/8 in proj)
    short8 aq[2];
    const ushort* qp = ws + (b*T_ + qt*64 + wv_id*16 + c)*H_;
    aq[0] = *(const short8*)(qp + g*8);
    aq[1] = *(const short8*)(qp + 32 + g*8);

    float m_ = -INFINITY, l_ = 0.f;     // per-lane state for q-row = c
    f32x4 o[4];
    #pragma unroll
    for (int jh = 0; jh < 4; ++jh) o[jh] = (f32x4){0.f, 0.f, 0.f, 0.f};

    short8 kreg0, kreg1, vreg0, vreg1;
    #define LOAD_TILES(kt_) do { \
        const ushort* ksrc = kg + ((kt_)*64 + sh)*H_ + ss*16;       \
        kreg0 = *(const short8*)ksrc; kreg1 = *(const short8*)(ksrc + 8); \
        const ushort* vsrc = vtg + sh*BT_ + (kt_)*64 + ss*16;       \
        vreg0 = *(const short8*)vsrc; vreg1 = *(const short8*)(vsrc + 8); \
    } while (0)
    #define WRITE_TILES(bi_) do { \
        *(short8*)&kls[bi_][sh][ss*16]     = kreg0; \
        *(short8*)&kls[bi_][sh][ss*16 + 8] = kreg1; \
        *(short8*)&vls[bi_][sh][ss*16]     = vreg0; \
        *(short8*)&vls[bi_][sh][ss*16 + 8] = vreg1; \
    } while (0)

    LOAD_TILES(0);
    WRITE_TILES(0);
    __syncthreads();

    int cur = 0;
    for (int kt = 0; kt < nkt; ++kt) {
        const bool more = (kt + 1 < nkt);
        if (more) LOAD_TILES(kt + 1);

        // S^T tile: s[j][r] = S[q = c][k = j*16 + g*4 + r]   (A = K rows, B = Q rows)
        f32x4 s[4];
        #pragma unroll
        for (int j = 0; j < 4; ++j) {
            f32x4 acc = {0.f, 0.f, 0.f, 0.f};
            #pragma unroll
            for (int ch = 0; ch < 2; ++ch) {
                const short8 bk = *(const short8*)(&kls[cur][j*16 + c][ch*32 + g*8]);
                acc = __builtin_amdgcn_mfma_f32_16x16x32_bf16(bk, aq[ch], acc, 0, 0, 0);
            }
            s[j] = acc;
        }

        // causal mask (diagonal tile only): k_loc = j*16+g*4+r, q_loc = wv_id*16+c
        if (kt == qt) {
            const int qloc = wv_id*16 + c;
            #pragma unroll
            for (int j = 0; j < 4; ++j)
                #pragma unroll
                for (int r = 0; r < 4; ++r)
                    if (j*16 + g*4 + r > qloc) s[j][r] = -1e30f;
        }

        // lane-local online softmax for q-row c (cross-g combine: xor 16, 32)
        float tm = s[0][0];
        #pragma unroll
        for (int j = 0; j < 4; ++j)
            #pragma unroll
            for (int r = 0; r < 4; ++r) tm = fmaxf(tm, s[j][r]);
        tm = fmaxf(tm, __shfl_xor(tm, 16));
        tm = fmaxf(tm, __shfl_xor(tm, 32));
        const float mn = fmaxf(m_, tm);
        const float al = __expf(m_ - mn);
        m_ = mn;
        float ps = 0.f;
        #pragma unroll
        for (int j = 0; j < 4; ++j)
            #pragma unroll
            for (int r = 0; r < 4; ++r) {
                const float p = __expf(s[j][r] - mn);
                s[j][r] = p;
                ps += p;
            }
        ps += __shfl_xor(ps, 16);
        ps += __shfl_xor(ps, 32);
        l_ = l_*al + ps;

        // redistribute rescale factor to PV output rows (q = g*4+r lives at lane g*4+r)
        #pragma unroll
        for (int r = 0; r < 4; ++r) {
            const float alr = __shfl(al, g*4 + r);
            #pragma unroll
            for (int jh = 0; jh < 4; ++jh) o[jh][r] *= alr;
        }

        // P -> LDS: lane owns P[q=c][k=j*16+g*4+(0..3)] -> 4 packed b64 writes
        #pragma unroll
        for (int j = 0; j < 4; ++j) {
            const uint lo = (uint)f2bf(s[j][0]) | ((uint)f2bf(s[j][1]) << 16);
            const uint hi = (uint)f2bf(s[j][2]) | ((uint)f2bf(s[j][3]) << 16);
            *(uint2*)&pls[wv_id][c][j*16 + g*4] = make_uint2(lo, hi);
        }

        // O += P V
        #pragma unroll
        for (int c2 = 0; c2 < 2; ++c2) {
            const short8 ap = *(const short8*)(&pls[wv_id][c][c2*32 + g*8]);
            #pragma unroll
            for (int jh = 0; jh < 4; ++jh) {
                const short8 bv = *(const short8*)(&vls[cur][jh*16 + c][c2*32 + g*8]);
                o[jh] = __builtin_amdgcn_mfma_f32_16x16x32_bf16(ap, bv, o[jh], 0, 0, 0);
            }
        }

        if (more) WRITE_TILES(cur ^ 1);
        __syncthreads();
        cur ^= 1;
    }

    // epilogue: fetch denom for q-row g*4+r from lane g*4+r
    float* op = out + (b*T_ + qt*64 + wv_id*16)*H_;
    #pragma unroll
    for (int r = 0; r < 4; ++r) {
        const float lr  = __shfl(l_, g*4 + r);
        const float inv = 1.0f / lr;
        #pragma unroll
        for (int jh = 0; jh < 4; ++jh)
            op[(g*4 + r)*H_ + jh*16 + c] = o[jh][r] * inv;
    }
    #undef LOAD_TILES
    #undef WRITE_TILES
}

extern "C" void kernel_launch(void* const* d_in, const int* in_sizes, int n_in,
                              void* d_out, int out_size, void* d_ws, size_t ws_size,
                              hipStream_t stream) {
    const float* x  = (const float*)d_in[0];
    const float* wq = (const float*)d_in[1];
    const float* wk = (const float*)d_in[2];
    const float* wv = (const float*)d_in[3];
    ushort* ws = (ushort*)d_ws;   // q,k [BT][H]; vT [H][BT]; wT[3][64][256] : ~9.5 MB

    prep_w_kernel<<<dim3(192), dim3(256), 0, stream>>>(wq, wk, wv, ws);
    qkv_proj_kernel<<<dim3(BT_/64), dim3(256), 0, stream>>>(x, ws);
    attn_kernel<<<dim3(B_*12), dim3(256), 0, stream>>>(ws, (float*)d_out);
}